// Round 1
// baseline (6335.112 us; speedup 1.0000x reference)
//
#include <hip/hip_runtime.h>
#include <hip/hip_bf16.h>

typedef float f32x4 __attribute__((ext_vector_type(4)));
typedef __bf16 bf16x8 __attribute__((ext_vector_type(8)));

__device__ __forceinline__ unsigned short f2b(float f) {
  unsigned u = __builtin_bit_cast(unsigned, f);
  unsigned r = (u + 0x7fffu + ((u >> 16) & 1u)) >> 16;   // RNE
  return (unsigned short)r;
}
__device__ __forceinline__ float b2f(unsigned short s) {
  return __builtin_bit_cast(float, ((unsigned)s) << 16);
}

// ---------------- transpose fp32 [R][C] -> bf16 [C][R] ----------------
__global__ __launch_bounds__(256) void tconv(const float* __restrict__ in,
                                             unsigned short* __restrict__ out,
                                             int R, int C) {
  __shared__ unsigned short tile[32][33];
  const int tx = threadIdx.x & 31, ty = threadIdx.x >> 5;
  const int c0 = blockIdx.x * 32, r0 = blockIdx.y * 32;
#pragma unroll
  for (int p = 0; p < 4; ++p) {
    int r = ty + p * 8;
    tile[r][tx] = f2b(in[(size_t)(r0 + r) * C + c0 + tx]);
  }
  __syncthreads();
#pragma unroll
  for (int p = 0; p < 4; ++p) {
    int cc = ty + p * 8;
    out[(size_t)(c0 + cc) * R + r0 + tx] = tile[tx][cc];
  }
}

// ---------------- combined bias prep: [4][1024] = bz, br, bhi, bhr ----
__global__ __launch_bounds__(256) void bprep(const float* __restrict__ bias,
                                             float* __restrict__ bc) {
  const int u = blockIdx.x * 256 + threadIdx.x;  // 0..1023
  bc[u]        = bias[u]        + bias[3072 + u];
  bc[1024 + u] = bias[1024 + u] + bias[4096 + u];
  bc[2048 + u] = bias[2048 + u];
  bc[3072 + u] = bias[5120 + u];
}

// ---------------- init: zero bf16 h, fp32 h, flags --------------------
__global__ __launch_bounds__(256) void hinit(unsigned short* __restrict__ hbf,
                                             float* __restrict__ h32,
                                             int* __restrict__ flags) {
  const int id = blockIdx.x * 256 + threadIdx.x;  // 65536 threads
  ((uint2*)hbf)[id] = make_uint2(0u, 0u);
  ((float4*)h32)[id] = make_float4(0.f, 0.f, 0.f, 0.f);
  if (id < 256) flags[id] = 0;
}

// ---------------- x projection chunk GEMM ------------------------------
// Out layout (bf16): xp[tl][cg(64)][gate(3)][b(256)][u16(16)]
__global__ __launch_bounds__(256) void xproj(
    const float* __restrict__ x,              // [256][256][512]
    const unsigned short* __restrict__ Wt,    // bf16 [3072][512]
    unsigned short* __restrict__ xp,
    int t0)
{
  __shared__ unsigned short A_s[128 * 32];
  __shared__ unsigned short B_s[128 * 32];
  const int tid = threadIdx.x;
  const int lane = tid & 63, w = tid >> 6;
  const int n0 = blockIdx.x * 128;
  const int r0 = blockIdx.y * 128;
  const int wm = w >> 1, wn = w & 1;
  const int u16l = lane & 15, kq = lane >> 4;

  f32x4 acc[4][4];
#pragma unroll
  for (int i = 0; i < 4; ++i)
#pragma unroll
    for (int j = 0; j < 4; ++j) acc[i][j] = 0.0f;

  const int srow = tid >> 1;     // 0..127
  const int skh = tid & 1;       // k half (16 elems)
  const int arow_g = r0 + srow;
  const int a_tl = arow_g >> 8, a_b = arow_g & 255;
  const float* asrc = x + ((size_t)a_b * 256 + t0 + a_tl) * 512 + skh * 16;
  const unsigned short* bsrc = Wt + (size_t)(n0 + srow) * 512 + skh * 16;

  for (int kt = 0; kt < 16; ++kt) {
    const int k0 = kt * 32;
    float4 af0 = *(const float4*)(asrc + k0);
    float4 af1 = *(const float4*)(asrc + k0 + 4);
    float4 af2 = *(const float4*)(asrc + k0 + 8);
    float4 af3 = *(const float4*)(asrc + k0 + 12);
    uint4 bv0 = *(const uint4*)(bsrc + k0);
    uint4 bv1 = *(const uint4*)(bsrc + k0 + 8);
    union { unsigned short s[8]; uint4 v; } p0, p1;
    p0.s[0] = f2b(af0.x); p0.s[1] = f2b(af0.y); p0.s[2] = f2b(af0.z); p0.s[3] = f2b(af0.w);
    p0.s[4] = f2b(af1.x); p0.s[5] = f2b(af1.y); p0.s[6] = f2b(af1.z); p0.s[7] = f2b(af1.w);
    p1.s[0] = f2b(af2.x); p1.s[1] = f2b(af2.y); p1.s[2] = f2b(af2.z); p1.s[3] = f2b(af2.w);
    p1.s[4] = f2b(af3.x); p1.s[5] = f2b(af3.y); p1.s[6] = f2b(af3.z); p1.s[7] = f2b(af3.w);
    __syncthreads();   // previous compute done before overwrite
    *(uint4*)&A_s[srow * 32 + skh * 16]     = p0.v;
    *(uint4*)&A_s[srow * 32 + skh * 16 + 8] = p1.v;
    *(uint4*)&B_s[srow * 32 + skh * 16]     = bv0;
    *(uint4*)&B_s[srow * 32 + skh * 16 + 8] = bv1;
    __syncthreads();
    bf16x8 afr[4], bfr[4];
#pragma unroll
    for (int i = 0; i < 4; ++i)
      afr[i] = *(const bf16x8*)&A_s[(wm * 64 + i * 16 + u16l) * 32 + kq * 8];
#pragma unroll
    for (int j = 0; j < 4; ++j)
      bfr[j] = *(const bf16x8*)&B_s[(wn * 64 + j * 16 + u16l) * 32 + kq * 8];
#pragma unroll
    for (int i = 0; i < 4; ++i)
#pragma unroll
      for (int j = 0; j < 4; ++j)
        acc[i][j] = __builtin_amdgcn_mfma_f32_16x16x32_bf16(afr[i], bfr[j], acc[i][j], 0, 0, 0);
  }

#pragma unroll
  for (int i = 0; i < 4; ++i)
#pragma unroll
    for (int j = 0; j < 4; ++j)
#pragma unroll
      for (int v = 0; v < 4; ++v) {
        const int gr = r0 + wm * 64 + i * 16 + kq * 4 + v;
        const int gc = n0 + wn * 64 + j * 16 + u16l;
        const int gate = gc >> 10, cg = (gc >> 4) & 63, uu = gc & 15;
        const int tl = gr >> 8, b = gr & 255;
        xp[(size_t)tl * 786432 + ((size_t)(cg * 3 + gate) * 256 + b) * 16 + uu] = f2b(acc[i][j][v]);
      }
}

__device__ __forceinline__ f32x4 up4(uint2 q) {
  f32x4 r;
  r[0] = b2f((unsigned short)(q.x & 0xffffu));
  r[1] = b2f((unsigned short)(q.x >> 16));
  r[2] = b2f((unsigned short)(q.y & 0xffffu));
  r[3] = b2f((unsigned short)(q.y >> 16));
  return r;
}

// ---------------- persistent GRU recurrence ----------------------------
// 256 blocks x 256 thr, 1 block/CU (LDS-bound). block = (rg = bid>>6,
// cg = bid&63): batch rows [rg*64, rg*64+64), u-cols [cg*16, cg*16+16).
// Ut slice (48 rows x 1024) staged fragment-major in LDS once.
// MFMA operand-swapped: A = Ut frag (LDS), B = h frag (global bf16).
// fp32 carry state lives in registers. Per-step sync: 64-block flag
// barrier per rg-group (groups are independent batch quarters).
__global__ __launch_bounds__(256, 1) void gru_persist(
    const unsigned short* __restrict__ xp,     // [CH][64][3][256][16] bf16
    const unsigned short* __restrict__ Ut,     // bf16 [3072][1024]
    const float* __restrict__ biasC,           // [4][1024]
    unsigned short* __restrict__ hbf0,         // bf16 [256][1024]
    unsigned short* __restrict__ hbf1,
    float* __restrict__ h32,                   // fp32 [256][1024] (chunk carry)
    int* __restrict__ flags,                   // [256]
    float* __restrict__ out,                   // fp32 [256][1024]
    int t0, int nsteps)
{
  extern __shared__ unsigned short Uls[];      // 98304 B
  const int tid = threadIdx.x;
  const int lane = tid & 63, w = tid >> 6;
  const int u16l = lane & 15, kq = lane >> 4;
  const int cg = blockIdx.x & 63, rg = blockIdx.x >> 6;

  // ---- stage Ut slice into LDS, fragment-major: frag f=(g*32+ks), 16B/lane
  for (int f = tid; f < 6144; f += 256) {
    const int ln = f & 63, ks = (f >> 6) & 31, g = f >> 11;
    const int row = g * 1024 + (cg << 4) + (ln & 15);
    const int col = ks * 32 + (ln >> 4) * 8;
    *(uint4*)&Uls[f * 8] = *(const uint4*)(Ut + (size_t)row * 1024 + col);
  }

  const int rb  = (rg << 6) + (w << 4) + u16l;   // this lane's batch row
  const int cu0 = (cg << 4) + (kq << 2);         // first of 4 owned u-cols
  const int lofs = lane << 3;                    // elems into LDS fragment

  const f32x4 bz4  = *(const f32x4*)(biasC + cu0);
  const f32x4 br4  = *(const f32x4*)(biasC + 1024 + cu0);
  const f32x4 bhi4 = *(const f32x4*)(biasC + 2048 + cu0);
  const f32x4 bhr4 = *(const f32x4*)(biasC + 3072 + cu0);

  f32x4 hold = *(const f32x4*)(h32 + (size_t)rb * 1024 + cu0);

  __syncthreads();

  for (int lt = 0; lt < nsteps; ++lt) {
    const int t = t0 + lt;
    const unsigned short* hin  = (t & 1) ? hbf1 : hbf0;
    unsigned short*       hout = (t & 1) ? hbf0 : hbf1;
    const unsigned short* xpt = xp + (size_t)lt * 786432;

    // epilogue operands — issue early so latency hides under the GEMM
    const unsigned short* xb = xpt + ((size_t)(cg * 3) * 256 + rb) * 16 + (kq << 2);
    const uint2 xzv = *(const uint2*)(xb);
    const uint2 xrv = *(const uint2*)(xb + 4096);
    const uint2 xhv = *(const uint2*)(xb + 8192);

    // preload all 32 B fragments (this lane's batch row of h, bf16)
    const unsigned short* hp = hin + ((size_t)rb << 10) + (kq << 3);
    bf16x8 bfrag[32];
#pragma unroll
    for (int ks = 0; ks < 32; ++ks)
      bfrag[ks] = *(const bf16x8*)(hp + ks * 32);

    f32x4 acc0 = {0.f, 0.f, 0.f, 0.f};
    f32x4 acc1 = {0.f, 0.f, 0.f, 0.f};
    f32x4 acc2 = {0.f, 0.f, 0.f, 0.f};
#pragma unroll
    for (int ks = 0; ks < 32; ++ks) {
      const bf16x8 a0 = *(const bf16x8*)&Uls[ks * 512 + lofs];
      const bf16x8 a1 = *(const bf16x8*)&Uls[16384 + ks * 512 + lofs];
      const bf16x8 a2 = *(const bf16x8*)&Uls[32768 + ks * 512 + lofs];
      const bf16x8 bb = bfrag[ks];
      acc0 = __builtin_amdgcn_mfma_f32_16x16x32_bf16(a0, bb, acc0, 0, 0, 0);
      acc1 = __builtin_amdgcn_mfma_f32_16x16x32_bf16(a1, bb, acc1, 0, 0, 0);
      acc2 = __builtin_amdgcn_mfma_f32_16x16x32_bf16(a2, bb, acc2, 0, 0, 0);
    }

    // epilogue: lane owns (batch rb, u-cols cu0..cu0+3)
    const f32x4 xz = up4(xzv), xr = up4(xrv), xh = up4(xhv);
    unsigned hw0 = 0, hw1 = 0;
#pragma unroll
    for (int v = 0; v < 4; ++v) {
      const float zpre = acc0[v] + xz[v] + bz4[v];
      const float rpre = acc1[v] + xr[v] + br4[v];
      const float rh   = acc2[v] + bhr4[v];
      const float z  = 1.f / (1.f + __expf(-zpre));
      const float rr = 1.f / (1.f + __expf(-rpre));
      const float hpre = xh[v] + bhi4[v] + rr * rh;
      const float e2 = __expf(2.f * hpre);
      const float hh = 1.f - 2.f / (e2 + 1.f);
      const float hnew = hh + z * (hold[v] - hh);
      hold[v] = hnew;
      const unsigned hb = (unsigned)f2b(hnew);
      if (v == 0) hw0 = hb;
      if (v == 1) hw0 |= hb << 16;
      if (v == 2) hw1 = hb;
      if (v == 3) hw1 |= hb << 16;
    }

    if (t == 255) {
      *(f32x4*)(out + (size_t)rb * 1024 + cu0) = hold;        // final fp32 state
    } else {
      *(uint2*)(hout + (size_t)rb * 1024 + cu0) = make_uint2(hw0, hw1);
    }

    // ---- rg-group barrier (64 blocks): release own flag, wait for group
    __syncthreads();   // all waves' stores drained to L2 (vmcnt0 before barrier)
    if (tid == 0)
      __hip_atomic_store(&flags[blockIdx.x], t + 1, __ATOMIC_RELEASE,
                         __HIP_MEMORY_SCOPE_AGENT);           // wbl2 + sc1 store
    if (w == 0) {
      const int want = t + 1;
      while (__hip_atomic_load(&flags[(rg << 6) | lane], __ATOMIC_RELAXED,
                               __HIP_MEMORY_SCOPE_AGENT) < want) {}
    }
    __syncthreads();
    __builtin_amdgcn_fence(__ATOMIC_ACQUIRE, "agent");        // inv L1/L2
  }

  // carry fp32 state to next chunk (if any)
  if (t0 + nsteps < 256)
    *(f32x4*)(h32 + (size_t)rb * 1024 + cu0) = hold;
}

extern "C" void kernel_launch(void* const* d_in, const int* in_sizes, int n_in,
                              void* d_out, int out_size, void* d_ws, size_t ws_size,
                              hipStream_t stream) {
  (void)in_sizes; (void)n_in; (void)out_size;
  const float* x    = (const float*)d_in[0];   // (256,256,512)
  const float* Wk   = (const float*)d_in[1];   // (512,3072)
  const float* Rk   = (const float*)d_in[2];   // (1024,3072)
  const float* bias = (const float*)d_in[3];   // (2,3072)
  float* out = (float*)d_out;

  char* ws = (char*)d_ws;
  unsigned short* Wt    = (unsigned short*)(ws + 0);         // 3,145,728 B
  unsigned short* Ut    = (unsigned short*)(ws + 3145728);   // 6,291,456 B
  float*          biasC = (float*)(ws + 9437184);            // 16,384 B
  unsigned short* hbf0  = (unsigned short*)(ws + 9453568);   // 524,288 B
  unsigned short* hbf1  = (unsigned short*)(ws + 9977856);   // 524,288 B
  float*          h32   = (float*)(ws + 10502144);           // 1,048,576 B
  int*            flags = (int*)(ws + 11550720);             // 4,096 B
  unsigned short* xp    = (unsigned short*)(ws + 11554816);  // CH * 1,572,864 B

  const size_t fixed_end = 11554816;
  int CH = 256;
  while (CH > 1 && fixed_end + (size_t)CH * 1572864 > ws_size) CH >>= 1;

  static int attr_set = 0;
  if (!attr_set) {
    (void)hipFuncSetAttribute((const void*)gru_persist,
                              hipFuncAttributeMaxDynamicSharedMemorySize, 98304);
    attr_set = 1;
  }

  tconv<<<dim3(96, 16), 256, 0, stream>>>(Wk, Wt, 512, 3072);
  tconv<<<dim3(96, 32), 256, 0, stream>>>(Rk, Ut, 1024, 3072);
  bprep<<<4, 256, 0, stream>>>(bias, biasC);
  hinit<<<256, 256, 0, stream>>>(hbf0, h32, flags);

  const int nch = 256 / CH;
  for (int c = 0; c < nch; ++c) {
    xproj<<<dim3(24, CH * 2), 256, 0, stream>>>(x, Wt, xp, c * CH);
    gru_persist<<<256, 256, 98304, stream>>>(xp, Ut, biasC, hbf0, hbf1, h32,
                                             flags, out, c * CH, CH);
  }
}

// Round 3
// 6022.224 us; speedup vs baseline: 1.0520x; 1.0520x over previous
//
#include <hip/hip_runtime.h>
#include <hip/hip_bf16.h>

typedef float f32x4 __attribute__((ext_vector_type(4)));
typedef __bf16 bf16x8 __attribute__((ext_vector_type(8)));
typedef unsigned int u32x2 __attribute__((ext_vector_type(2)));

__device__ __forceinline__ unsigned short f2b(float f) {
  unsigned u = __builtin_bit_cast(unsigned, f);
  unsigned r = (u + 0x7fffu + ((u >> 16) & 1u)) >> 16;   // RNE
  return (unsigned short)r;
}
__device__ __forceinline__ float b2f(unsigned short s) {
  return __builtin_bit_cast(float, ((unsigned)s) << 16);
}

// ---------------- transpose fp32 [R][C] -> bf16 [C][R] ----------------
__global__ __launch_bounds__(256) void tconv(const float* __restrict__ in,
                                             unsigned short* __restrict__ out,
                                             int R, int C) {
  __shared__ unsigned short tile[32][33];
  const int tx = threadIdx.x & 31, ty = threadIdx.x >> 5;
  const int c0 = blockIdx.x * 32, r0 = blockIdx.y * 32;
#pragma unroll
  for (int p = 0; p < 4; ++p) {
    int r = ty + p * 8;
    tile[r][tx] = f2b(in[(size_t)(r0 + r) * C + c0 + tx]);
  }
  __syncthreads();
#pragma unroll
  for (int p = 0; p < 4; ++p) {
    int cc = ty + p * 8;
    out[(size_t)(c0 + cc) * R + r0 + tx] = tile[tx][cc];
  }
}

// ---------------- combined bias prep: [4][1024] = bz, br, bhi, bhr ----
__global__ __launch_bounds__(256) void bprep(const float* __restrict__ bias,
                                             float* __restrict__ bc) {
  const int u = blockIdx.x * 256 + threadIdx.x;  // 0..1023
  bc[u]        = bias[u]        + bias[3072 + u];
  bc[1024 + u] = bias[1024 + u] + bias[4096 + u];
  bc[2048 + u] = bias[2048 + u];
  bc[3072 + u] = bias[5120 + u];
}

// ---------------- init: zero bf16 h, fp32 h, flags --------------------
__global__ __launch_bounds__(256) void hinit(unsigned short* __restrict__ hbf,
                                             float* __restrict__ h32,
                                             int* __restrict__ flags) {
  const int id = blockIdx.x * 256 + threadIdx.x;  // 65536 threads
  ((uint2*)hbf)[id] = make_uint2(0u, 0u);
  ((float4*)h32)[id] = make_float4(0.f, 0.f, 0.f, 0.f);
  if (id < 256) flags[id] = 0;
}

// ---------------- x projection chunk GEMM ------------------------------
// Out layout (bf16): xp[tl][cg(64)][gate(3)][b(256)][u16(16)]
__global__ __launch_bounds__(256) void xproj(
    const float* __restrict__ x,              // [256][256][512]
    const unsigned short* __restrict__ Wt,    // bf16 [3072][512]
    unsigned short* __restrict__ xp,
    int t0)
{
  __shared__ unsigned short A_s[128 * 32];
  __shared__ unsigned short B_s[128 * 32];
  const int tid = threadIdx.x;
  const int lane = tid & 63, w = tid >> 6;
  const int n0 = blockIdx.x * 128;
  const int r0 = blockIdx.y * 128;
  const int wm = w >> 1, wn = w & 1;
  const int u16l = lane & 15, kq = lane >> 4;

  f32x4 acc[4][4];
#pragma unroll
  for (int i = 0; i < 4; ++i)
#pragma unroll
    for (int j = 0; j < 4; ++j) acc[i][j] = 0.0f;

  const int srow = tid >> 1;     // 0..127
  const int skh = tid & 1;       // k half (16 elems)
  const int arow_g = r0 + srow;
  const int a_tl = arow_g >> 8, a_b = arow_g & 255;
  const float* asrc = x + ((size_t)a_b * 256 + t0 + a_tl) * 512 + skh * 16;
  const unsigned short* bsrc = Wt + (size_t)(n0 + srow) * 512 + skh * 16;

  for (int kt = 0; kt < 16; ++kt) {
    const int k0 = kt * 32;
    float4 af0 = *(const float4*)(asrc + k0);
    float4 af1 = *(const float4*)(asrc + k0 + 4);
    float4 af2 = *(const float4*)(asrc + k0 + 8);
    float4 af3 = *(const float4*)(asrc + k0 + 12);
    uint4 bv0 = *(const uint4*)(bsrc + k0);
    uint4 bv1 = *(const uint4*)(bsrc + k0 + 8);
    union { unsigned short s[8]; uint4 v; } p0, p1;
    p0.s[0] = f2b(af0.x); p0.s[1] = f2b(af0.y); p0.s[2] = f2b(af0.z); p0.s[3] = f2b(af0.w);
    p0.s[4] = f2b(af1.x); p0.s[5] = f2b(af1.y); p0.s[6] = f2b(af1.z); p0.s[7] = f2b(af1.w);
    p1.s[0] = f2b(af2.x); p1.s[1] = f2b(af2.y); p1.s[2] = f2b(af2.z); p1.s[3] = f2b(af2.w);
    p1.s[4] = f2b(af3.x); p1.s[5] = f2b(af3.y); p1.s[6] = f2b(af3.z); p1.s[7] = f2b(af3.w);
    __syncthreads();   // previous compute done before overwrite
    *(uint4*)&A_s[srow * 32 + skh * 16]     = p0.v;
    *(uint4*)&A_s[srow * 32 + skh * 16 + 8] = p1.v;
    *(uint4*)&B_s[srow * 32 + skh * 16]     = bv0;
    *(uint4*)&B_s[srow * 32 + skh * 16 + 8] = bv1;
    __syncthreads();
    bf16x8 afr[4], bfr[4];
#pragma unroll
    for (int i = 0; i < 4; ++i)
      afr[i] = *(const bf16x8*)&A_s[(wm * 64 + i * 16 + u16l) * 32 + kq * 8];
#pragma unroll
    for (int j = 0; j < 4; ++j)
      bfr[j] = *(const bf16x8*)&B_s[(wn * 64 + j * 16 + u16l) * 32 + kq * 8];
#pragma unroll
    for (int i = 0; i < 4; ++i)
#pragma unroll
      for (int j = 0; j < 4; ++j)
        acc[i][j] = __builtin_amdgcn_mfma_f32_16x16x32_bf16(afr[i], bfr[j], acc[i][j], 0, 0, 0);
  }

#pragma unroll
  for (int i = 0; i < 4; ++i)
#pragma unroll
    for (int j = 0; j < 4; ++j)
#pragma unroll
      for (int v = 0; v < 4; ++v) {
        const int gr = r0 + wm * 64 + i * 16 + kq * 4 + v;
        const int gc = n0 + wn * 64 + j * 16 + u16l;
        const int gate = gc >> 10, cg = (gc >> 4) & 63, uu = gc & 15;
        const int tl = gr >> 8, b = gr & 255;
        xp[(size_t)tl * 786432 + ((size_t)(cg * 3 + gate) * 256 + b) * 16 + uu] = f2b(acc[i][j][v]);
      }
}

__device__ __forceinline__ f32x4 up4(u32x2 q) {
  f32x4 r;
  r[0] = b2f((unsigned short)(q[0] & 0xffffu));
  r[1] = b2f((unsigned short)(q[0] >> 16));
  r[2] = b2f((unsigned short)(q[1] & 0xffffu));
  r[3] = b2f((unsigned short)(q[1] >> 16));
  return r;
}

// ---------------- persistent GRU recurrence ----------------------------
// 256 blocks x 256 thr, 1 block/CU (LDS-bound). block = (rg = bid>>6,
// cg = bid&63). Ut slice in LDS once. Sync path IDENTICAL to the
// round-1 hardware-verified version (release flag store + relaxed spin
// + agent acquire fence). The only change vs round 1: all 32 h-fragment
// loads are force-issued via inline asm into held VGPRs (deep in
// flight, ~128 KB/CU) with counted vmcnt waits, so the per-step L3
// h-exchange is bandwidth- instead of latency-limited.
__global__ __launch_bounds__(256, 1) void gru_persist(
    const unsigned short* __restrict__ xp,     // [CH][64][3][256][16] bf16
    const unsigned short* __restrict__ Ut,     // bf16 [3072][1024]
    const float* __restrict__ biasC,           // [4][1024]
    unsigned short* __restrict__ hbf0,         // bf16 [256][1024]
    unsigned short* __restrict__ hbf1,
    float* __restrict__ h32,                   // fp32 [256][1024] (chunk carry)
    int* __restrict__ flags,                   // [256]
    float* __restrict__ out,                   // fp32 [256][1024]
    int t0, int nsteps)
{
  extern __shared__ unsigned short Uls[];      // 98304 B
  const int tid = threadIdx.x;
  const int lane = tid & 63, w = tid >> 6;
  const int u16l = lane & 15, kq = lane >> 4;
  const int cg = blockIdx.x & 63, rg = blockIdx.x >> 6;

  // ---- stage Ut slice into LDS, fragment-major: frag f=(g*32+ks), 16B/lane
  for (int f = tid; f < 6144; f += 256) {
    const int ln = f & 63, ks = (f >> 6) & 31, g = f >> 11;
    const int row = g * 1024 + (cg << 4) + (ln & 15);
    const int col = ks * 32 + (ln >> 4) * 8;
    *(uint4*)&Uls[f * 8] = *(const uint4*)(Ut + (size_t)row * 1024 + col);
  }

  const int rb  = (rg << 6) + (w << 4) + u16l;   // this lane's batch row
  const int cu0 = (cg << 4) + (kq << 2);         // first of 4 owned u-cols
  const int lofs = lane << 3;                    // elems into LDS fragment

  const f32x4 bz4  = *(const f32x4*)(biasC + cu0);
  const f32x4 br4  = *(const f32x4*)(biasC + 1024 + cu0);
  const f32x4 bhi4 = *(const f32x4*)(biasC + 2048 + cu0);
  const f32x4 bhr4 = *(const f32x4*)(biasC + 3072 + cu0);

  f32x4 hold = *(const f32x4*)(h32 + (size_t)rb * 1024 + cu0);

  __syncthreads();

  for (int lt = 0; lt < nsteps; ++lt) {
    const int t = t0 + lt;
    const unsigned short* hin  = (t & 1) ? hbf1 : hbf0;
    unsigned short*       hout = (t & 1) ? hbf0 : hbf1;
    const unsigned short* xpt = xp + (size_t)lt * 786432;
    const unsigned short* hp = hin + ((size_t)rb << 10) + (kq << 3);

    // force-issue ALL 32 h-fragment loads (held in 128 VGPRs -> deep
    // in flight; freshness guaranteed by prior step's acquire fence)
    f32x4 hbuf[32];
#pragma unroll
    for (int ks = 0; ks < 32; ++ks)
      asm volatile("global_load_dwordx4 %0, %1, off offset:%2"
                   : "=v"(hbuf[ks]) : "v"(hp), "i"(ks * 64) : "memory");

    // epilogue operands, issued behind the h loads (counted below)
    const unsigned short* xb = xpt + ((size_t)(cg * 3) * 256 + rb) * 16 + (kq << 2);
    u32x2 xzv, xrv, xhv;
    asm volatile("global_load_dwordx2 %0, %1, off" : "=v"(xzv) : "v"(xb) : "memory");
    asm volatile("global_load_dwordx2 %0, %1, off" : "=v"(xrv) : "v"(xb + 4096) : "memory");
    asm volatile("global_load_dwordx2 %0, %1, off" : "=v"(xhv) : "v"(xb + 8192) : "memory");

    f32x4 acc0 = {0.f, 0.f, 0.f, 0.f};
    f32x4 acc1 = {0.f, 0.f, 0.f, 0.f};
    f32x4 acc2 = {0.f, 0.f, 0.f, 0.f};

    // half 1 needs h frags 0..15: outstanding <= 16 h + 3 xp = 19
    asm volatile("s_waitcnt vmcnt(19)" ::: "memory");
    __builtin_amdgcn_sched_barrier(0);
#pragma unroll
    for (int ks = 0; ks < 16; ++ks) {
      const bf16x8 a0 = *(const bf16x8*)&Uls[ks * 512 + lofs];
      const bf16x8 a1 = *(const bf16x8*)&Uls[16384 + ks * 512 + lofs];
      const bf16x8 a2 = *(const bf16x8*)&Uls[32768 + ks * 512 + lofs];
      const bf16x8 bb = __builtin_bit_cast(bf16x8, hbuf[ks]);
      acc0 = __builtin_amdgcn_mfma_f32_16x16x32_bf16(a0, bb, acc0, 0, 0, 0);
      acc1 = __builtin_amdgcn_mfma_f32_16x16x32_bf16(a1, bb, acc1, 0, 0, 0);
      acc2 = __builtin_amdgcn_mfma_f32_16x16x32_bf16(a2, bb, acc2, 0, 0, 0);
    }
    // half 2 needs all h frags: outstanding <= 3 xp
    asm volatile("s_waitcnt vmcnt(3)" ::: "memory");
    __builtin_amdgcn_sched_barrier(0);
#pragma unroll
    for (int ks = 16; ks < 32; ++ks) {
      const bf16x8 a0 = *(const bf16x8*)&Uls[ks * 512 + lofs];
      const bf16x8 a1 = *(const bf16x8*)&Uls[16384 + ks * 512 + lofs];
      const bf16x8 a2 = *(const bf16x8*)&Uls[32768 + ks * 512 + lofs];
      const bf16x8 bb = __builtin_bit_cast(bf16x8, hbuf[ks]);
      acc0 = __builtin_amdgcn_mfma_f32_16x16x32_bf16(a0, bb, acc0, 0, 0, 0);
      acc1 = __builtin_amdgcn_mfma_f32_16x16x32_bf16(a1, bb, acc1, 0, 0, 0);
      acc2 = __builtin_amdgcn_mfma_f32_16x16x32_bf16(a2, bb, acc2, 0, 0, 0);
    }
    asm volatile("s_waitcnt vmcnt(0)" ::: "memory");
    __builtin_amdgcn_sched_barrier(0);

    // epilogue: lane owns (batch rb, u-cols cu0..cu0+3)
    const f32x4 xz = up4(xzv), xr = up4(xrv), xh = up4(xhv);
    unsigned hw0 = 0, hw1 = 0;
#pragma unroll
    for (int v = 0; v < 4; ++v) {
      const float zpre = acc0[v] + xz[v] + bz4[v];
      const float rpre = acc1[v] + xr[v] + br4[v];
      const float rh   = acc2[v] + bhr4[v];
      const float z  = 1.f / (1.f + __expf(-zpre));
      const float rr = 1.f / (1.f + __expf(-rpre));
      const float hpre = xh[v] + bhi4[v] + rr * rh;
      const float e2 = __expf(2.f * hpre);
      const float hh = 1.f - 2.f / (e2 + 1.f);
      const float hnew = hh + z * (hold[v] - hh);
      hold[v] = hnew;
      const unsigned hb = (unsigned)f2b(hnew);
      if (v == 0) hw0 = hb;
      if (v == 1) hw0 |= hb << 16;
      if (v == 2) hw1 = hb;
      if (v == 3) hw1 |= hb << 16;
    }

    if (t == 255) {
      *(f32x4*)(out + (size_t)rb * 1024 + cu0) = hold;        // final fp32 state
    } else {
      *(uint2*)(hout + (size_t)rb * 1024 + cu0) = make_uint2(hw0, hw1);
    }

    // ---- rg-group barrier (64 blocks) — round-1-verified construct:
    __syncthreads();   // all waves' stores drained (vmcnt0 before barrier)
    if (tid == 0)
      __hip_atomic_store(&flags[blockIdx.x], t + 1, __ATOMIC_RELEASE,
                         __HIP_MEMORY_SCOPE_AGENT);           // wbl2 + store
    if (w == 0) {
      const int want = t + 1;
      while (__hip_atomic_load(&flags[(rg << 6) | lane], __ATOMIC_RELAXED,
                               __HIP_MEMORY_SCOPE_AGENT) < want) {}
    }
    __syncthreads();
    __builtin_amdgcn_fence(__ATOMIC_ACQUIRE, "agent");        // inv caches
  }

  // carry fp32 state to next chunk (if any)
  if (t0 + nsteps < 256)
    *(f32x4*)(h32 + (size_t)rb * 1024 + cu0) = hold;
}

extern "C" void kernel_launch(void* const* d_in, const int* in_sizes, int n_in,
                              void* d_out, int out_size, void* d_ws, size_t ws_size,
                              hipStream_t stream) {
  (void)in_sizes; (void)n_in; (void)out_size;
  const float* x    = (const float*)d_in[0];   // (256,256,512)
  const float* Wk   = (const float*)d_in[1];   // (512,3072)
  const float* Rk   = (const float*)d_in[2];   // (1024,3072)
  const float* bias = (const float*)d_in[3];   // (2,3072)
  float* out = (float*)d_out;

  char* ws = (char*)d_ws;
  unsigned short* Wt    = (unsigned short*)(ws + 0);         // 3,145,728 B
  unsigned short* Ut    = (unsigned short*)(ws + 3145728);   // 6,291,456 B
  float*          biasC = (float*)(ws + 9437184);            // 16,384 B
  unsigned short* hbf0  = (unsigned short*)(ws + 9453568);   // 524,288 B
  unsigned short* hbf1  = (unsigned short*)(ws + 9977856);   // 524,288 B
  float*          h32   = (float*)(ws + 10502144);           // 1,048,576 B
  int*            flags = (int*)(ws + 11550720);             // 4,096 B
  unsigned short* xp    = (unsigned short*)(ws + 11554816);  // CH * 1,572,864 B

  const size_t fixed_end = 11554816;
  int CH = 256;
  while (CH > 1 && fixed_end + (size_t)CH * 1572864 > ws_size) CH >>= 1;

  static int attr_set = 0;
  if (!attr_set) {
    (void)hipFuncSetAttribute((const void*)gru_persist,
                              hipFuncAttributeMaxDynamicSharedMemorySize, 98304);
    attr_set = 1;
  }

  tconv<<<dim3(96, 16), 256, 0, stream>>>(Wk, Wt, 512, 3072);
  tconv<<<dim3(96, 32), 256, 0, stream>>>(Rk, Ut, 1024, 3072);
  bprep<<<4, 256, 0, stream>>>(bias, biasC);
  hinit<<<256, 256, 0, stream>>>(hbf0, h32, flags);

  const int nch = 256 / CH;
  for (int c = 0; c < nch; ++c) {
    xproj<<<dim3(24, CH * 2), 256, 0, stream>>>(x, Wt, xp, c * CH);
    gru_persist<<<256, 256, 98304, stream>>>(xp, Ut, biasC, hbf0, hbf1, h32,
                                             flags, out, c * CH, CH);
  }
}

// Round 4
// 2382.852 us; speedup vs baseline: 2.6586x; 2.5273x over previous
//
#include <hip/hip_runtime.h>
#include <hip/hip_bf16.h>

typedef float f32x4 __attribute__((ext_vector_type(4)));
typedef __bf16 bf16x8 __attribute__((ext_vector_type(8)));
typedef unsigned int u32x2 __attribute__((ext_vector_type(2)));

__device__ __forceinline__ unsigned short f2b(float f) {
  unsigned u = __builtin_bit_cast(unsigned, f);
  unsigned r = (u + 0x7fffu + ((u >> 16) & 1u)) >> 16;   // RNE
  return (unsigned short)r;
}
__device__ __forceinline__ float b2f(unsigned short s) {
  return __builtin_bit_cast(float, ((unsigned)s) << 16);
}

// ---------------- transpose fp32 [R][C] -> bf16 [C][R] ----------------
__global__ __launch_bounds__(256) void tconv(const float* __restrict__ in,
                                             unsigned short* __restrict__ out,
                                             int R, int C) {
  __shared__ unsigned short tile[32][33];
  const int tx = threadIdx.x & 31, ty = threadIdx.x >> 5;
  const int c0 = blockIdx.x * 32, r0 = blockIdx.y * 32;
#pragma unroll
  for (int p = 0; p < 4; ++p) {
    int r = ty + p * 8;
    tile[r][tx] = f2b(in[(size_t)(r0 + r) * C + c0 + tx]);
  }
  __syncthreads();
#pragma unroll
  for (int p = 0; p < 4; ++p) {
    int cc = ty + p * 8;
    out[(size_t)(c0 + cc) * R + r0 + tx] = tile[tx][cc];
  }
}

// ---------------- combined bias prep: [4][1024] = bz, br, bhi, bhr ----
__global__ __launch_bounds__(256) void bprep(const float* __restrict__ bias,
                                             float* __restrict__ bc) {
  const int u = blockIdx.x * 256 + threadIdx.x;  // 0..1023
  bc[u]        = bias[u]        + bias[3072 + u];
  bc[1024 + u] = bias[1024 + u] + bias[4096 + u];
  bc[2048 + u] = bias[2048 + u];
  bc[3072 + u] = bias[5120 + u];
}

// ---------------- init: zero bf16 h, fp32 h, flags --------------------
__global__ __launch_bounds__(256) void hinit(unsigned short* __restrict__ hbf,
                                             float* __restrict__ h32,
                                             int* __restrict__ flags) {
  const int id = blockIdx.x * 256 + threadIdx.x;  // 65536 threads
  ((uint2*)hbf)[id] = make_uint2(0u, 0u);
  ((float4*)h32)[id] = make_float4(0.f, 0.f, 0.f, 0.f);
  if (id < 4096) flags[id] = 0;   // 256 flags padded to 64B lines
}

// ---------------- x projection chunk GEMM ------------------------------
// Out layout (bf16): xp[tl][cg(64)][gate(3)][b(256)][u16(16)]
__global__ __launch_bounds__(256) void xproj(
    const float* __restrict__ x,              // [256][256][512]
    const unsigned short* __restrict__ Wt,    // bf16 [3072][512]
    unsigned short* __restrict__ xp,
    int t0)
{
  __shared__ unsigned short A_s[128 * 32];
  __shared__ unsigned short B_s[128 * 32];
  const int tid = threadIdx.x;
  const int lane = tid & 63, w = tid >> 6;
  const int n0 = blockIdx.x * 128;
  const int r0 = blockIdx.y * 128;
  const int wm = w >> 1, wn = w & 1;
  const int u16l = lane & 15, kq = lane >> 4;

  f32x4 acc[4][4];
#pragma unroll
  for (int i = 0; i < 4; ++i)
#pragma unroll
    for (int j = 0; j < 4; ++j) acc[i][j] = 0.0f;

  const int srow = tid >> 1;     // 0..127
  const int skh = tid & 1;       // k half (16 elems)
  const int arow_g = r0 + srow;
  const int a_tl = arow_g >> 8, a_b = arow_g & 255;
  const float* asrc = x + ((size_t)a_b * 256 + t0 + a_tl) * 512 + skh * 16;
  const unsigned short* bsrc = Wt + (size_t)(n0 + srow) * 512 + skh * 16;

  for (int kt = 0; kt < 16; ++kt) {
    const int k0 = kt * 32;
    float4 af0 = *(const float4*)(asrc + k0);
    float4 af1 = *(const float4*)(asrc + k0 + 4);
    float4 af2 = *(const float4*)(asrc + k0 + 8);
    float4 af3 = *(const float4*)(asrc + k0 + 12);
    uint4 bv0 = *(const uint4*)(bsrc + k0);
    uint4 bv1 = *(const uint4*)(bsrc + k0 + 8);
    union { unsigned short s[8]; uint4 v; } p0, p1;
    p0.s[0] = f2b(af0.x); p0.s[1] = f2b(af0.y); p0.s[2] = f2b(af0.z); p0.s[3] = f2b(af0.w);
    p0.s[4] = f2b(af1.x); p0.s[5] = f2b(af1.y); p0.s[6] = f2b(af1.z); p0.s[7] = f2b(af1.w);
    p1.s[0] = f2b(af2.x); p1.s[1] = f2b(af2.y); p1.s[2] = f2b(af2.z); p1.s[3] = f2b(af2.w);
    p1.s[4] = f2b(af3.x); p1.s[5] = f2b(af3.y); p1.s[6] = f2b(af3.z); p1.s[7] = f2b(af3.w);
    __syncthreads();   // previous compute done before overwrite
    *(uint4*)&A_s[srow * 32 + skh * 16]     = p0.v;
    *(uint4*)&A_s[srow * 32 + skh * 16 + 8] = p1.v;
    *(uint4*)&B_s[srow * 32 + skh * 16]     = bv0;
    *(uint4*)&B_s[srow * 32 + skh * 16 + 8] = bv1;
    __syncthreads();
    bf16x8 afr[4], bfr[4];
#pragma unroll
    for (int i = 0; i < 4; ++i)
      afr[i] = *(const bf16x8*)&A_s[(wm * 64 + i * 16 + u16l) * 32 + kq * 8];
#pragma unroll
    for (int j = 0; j < 4; ++j)
      bfr[j] = *(const bf16x8*)&B_s[(wn * 64 + j * 16 + u16l) * 32 + kq * 8];
#pragma unroll
    for (int i = 0; i < 4; ++i)
#pragma unroll
      for (int j = 0; j < 4; ++j)
        acc[i][j] = __builtin_amdgcn_mfma_f32_16x16x32_bf16(afr[i], bfr[j], acc[i][j], 0, 0, 0);
  }

#pragma unroll
  for (int i = 0; i < 4; ++i)
#pragma unroll
    for (int j = 0; j < 4; ++j)
#pragma unroll
      for (int v = 0; v < 4; ++v) {
        const int gr = r0 + wm * 64 + i * 16 + kq * 4 + v;
        const int gc = n0 + wn * 64 + j * 16 + u16l;
        const int gate = gc >> 10, cg = (gc >> 4) & 63, uu = gc & 15;
        const int tl = gr >> 8, b = gr & 255;
        xp[(size_t)tl * 786432 + ((size_t)(cg * 3 + gate) * 256 + b) * 16 + uu] = f2b(acc[i][j][v]);
      }
}

__device__ __forceinline__ f32x4 up4(u32x2 q) {
  f32x4 r;
  r[0] = b2f((unsigned short)(q[0] & 0xffffu));
  r[1] = b2f((unsigned short)(q[0] >> 16));
  r[2] = b2f((unsigned short)(q[1] & 0xffffu));
  r[3] = b2f((unsigned short)(q[1] >> 16));
  return r;
}

// ---------------- persistent GRU recurrence (fence-free) ---------------
// 256 blocks x 256 thr, 1 block/CU. block = (rg = bid>>6, cg = bid&63).
// Ut slice in LDS once. ALL cross-XCD h traffic goes through L3 via
// sc1 (agent-coherent) loads/stores — NO buffer_wbl2 / buffer_inv in
// the loop. Step signal = atomic fetch_add (RMW executes at L3, cannot
// be lost -> no deadlock mode); spin = relaxed agent loads (HW-verified
// to observe remote updates in round 1).
__global__ __launch_bounds__(256, 1) void gru_persist(
    const unsigned short* __restrict__ xp,     // [CH][64][3][256][16] bf16
    const unsigned short* __restrict__ Ut,     // bf16 [3072][1024]
    const float* __restrict__ biasC,           // [4][1024]
    unsigned short* __restrict__ hbf0,         // bf16 [256][1024]
    unsigned short* __restrict__ hbf1,
    float* __restrict__ h32,                   // fp32 [256][1024] (chunk carry)
    int* __restrict__ flags,                   // [256*16] (64B-padded)
    float* __restrict__ out,                   // fp32 [256][1024]
    int t0, int nsteps)
{
  extern __shared__ unsigned short Uls[];      // 98304 B
  const int tid = threadIdx.x;
  const int lane = tid & 63, w = tid >> 6;
  const int u16l = lane & 15, kq = lane >> 4;
  const int cg = blockIdx.x & 63, rg = blockIdx.x >> 6;

  // ---- stage Ut slice into LDS, fragment-major: frag f=(g*32+ks), 16B/lane
  for (int f = tid; f < 6144; f += 256) {
    const int ln = f & 63, ks = (f >> 6) & 31, g = f >> 11;
    const int row = g * 1024 + (cg << 4) + (ln & 15);
    const int col = ks * 32 + (ln >> 4) * 8;
    *(uint4*)&Uls[f * 8] = *(const uint4*)(Ut + (size_t)row * 1024 + col);
  }

  const int rb  = (rg << 6) + (w << 4) + u16l;   // this lane's batch row
  const int cu0 = (cg << 4) + (kq << 2);         // first of 4 owned u-cols
  const int lofs = lane << 3;                    // elems into LDS fragment

  const f32x4 bz4  = *(const f32x4*)(biasC + cu0);
  const f32x4 br4  = *(const f32x4*)(biasC + 1024 + cu0);
  const f32x4 bhi4 = *(const f32x4*)(biasC + 2048 + cu0);
  const f32x4 bhr4 = *(const f32x4*)(biasC + 3072 + cu0);

  f32x4 hold = *(const f32x4*)(h32 + (size_t)rb * 1024 + cu0);

  __syncthreads();

  for (int lt = 0; lt < nsteps; ++lt) {
    const int t = t0 + lt;
    const unsigned short* hin  = (t & 1) ? hbf1 : hbf0;
    unsigned short*       hout = (t & 1) ? hbf0 : hbf1;
    const unsigned short* xpt = xp + (size_t)lt * 786432;
    const unsigned short* hp = hin + ((size_t)rb << 10) + (kq << 3);

    // force-issue ALL 32 h-fragment loads, agent-coherent (L3-served),
    // held deep in flight (~128 KB/CU)
    f32x4 hbuf[32];
#pragma unroll
    for (int ks = 0; ks < 32; ++ks)
      asm volatile("global_load_dwordx4 %0, %1, off offset:%2 sc1"
                   : "=v"(hbuf[ks]) : "v"(hp), "i"(ks * 64) : "memory");

    // epilogue operands, plain cached loads (read-only data, L2 stays warm)
    const unsigned short* xb = xpt + ((size_t)(cg * 3) * 256 + rb) * 16 + (kq << 2);
    u32x2 xzv, xrv, xhv;
    asm volatile("global_load_dwordx2 %0, %1, off" : "=v"(xzv) : "v"(xb) : "memory");
    asm volatile("global_load_dwordx2 %0, %1, off" : "=v"(xrv) : "v"(xb + 4096) : "memory");
    asm volatile("global_load_dwordx2 %0, %1, off" : "=v"(xhv) : "v"(xb + 8192) : "memory");

    f32x4 acc0 = {0.f, 0.f, 0.f, 0.f};
    f32x4 acc1 = {0.f, 0.f, 0.f, 0.f};
    f32x4 acc2 = {0.f, 0.f, 0.f, 0.f};

    // half 1 needs h frags 0..15: outstanding <= 16 h + 3 xp = 19
    asm volatile("s_waitcnt vmcnt(19)" ::: "memory");
    __builtin_amdgcn_sched_barrier(0);
#pragma unroll
    for (int ks = 0; ks < 16; ++ks) {
      const bf16x8 a0 = *(const bf16x8*)&Uls[ks * 512 + lofs];
      const bf16x8 a1 = *(const bf16x8*)&Uls[16384 + ks * 512 + lofs];
      const bf16x8 a2 = *(const bf16x8*)&Uls[32768 + ks * 512 + lofs];
      const bf16x8 bb = __builtin_bit_cast(bf16x8, hbuf[ks]);
      acc0 = __builtin_amdgcn_mfma_f32_16x16x32_bf16(a0, bb, acc0, 0, 0, 0);
      acc1 = __builtin_amdgcn_mfma_f32_16x16x32_bf16(a1, bb, acc1, 0, 0, 0);
      acc2 = __builtin_amdgcn_mfma_f32_16x16x32_bf16(a2, bb, acc2, 0, 0, 0);
    }
    // half 2 needs all h frags: outstanding <= 3 xp
    asm volatile("s_waitcnt vmcnt(3)" ::: "memory");
    __builtin_amdgcn_sched_barrier(0);
#pragma unroll
    for (int ks = 16; ks < 32; ++ks) {
      const bf16x8 a0 = *(const bf16x8*)&Uls[ks * 512 + lofs];
      const bf16x8 a1 = *(const bf16x8*)&Uls[16384 + ks * 512 + lofs];
      const bf16x8 a2 = *(const bf16x8*)&Uls[32768 + ks * 512 + lofs];
      const bf16x8 bb = __builtin_bit_cast(bf16x8, hbuf[ks]);
      acc0 = __builtin_amdgcn_mfma_f32_16x16x32_bf16(a0, bb, acc0, 0, 0, 0);
      acc1 = __builtin_amdgcn_mfma_f32_16x16x32_bf16(a1, bb, acc1, 0, 0, 0);
      acc2 = __builtin_amdgcn_mfma_f32_16x16x32_bf16(a2, bb, acc2, 0, 0, 0);
    }
    asm volatile("s_waitcnt vmcnt(0)" ::: "memory");
    __builtin_amdgcn_sched_barrier(0);

    // epilogue: lane owns (batch rb, u-cols cu0..cu0+3)
    const f32x4 xz = up4(xzv), xr = up4(xrv), xh = up4(xhv);
    unsigned hw0 = 0, hw1 = 0;
#pragma unroll
    for (int v = 0; v < 4; ++v) {
      const float zpre = acc0[v] + xz[v] + bz4[v];
      const float rpre = acc1[v] + xr[v] + br4[v];
      const float rh   = acc2[v] + bhr4[v];
      const float z  = 1.f / (1.f + __expf(-zpre));
      const float rr = 1.f / (1.f + __expf(-rpre));
      const float hpre = xh[v] + bhi4[v] + rr * rh;
      const float e2 = __expf(2.f * hpre);
      const float hh = 1.f - 2.f / (e2 + 1.f);
      const float hnew = hh + z * (hold[v] - hh);
      hold[v] = hnew;
      const unsigned hb = (unsigned)f2b(hnew);
      if (v == 0) hw0 = hb;
      if (v == 1) hw0 |= hb << 16;
      if (v == 2) hw1 = hb;
      if (v == 3) hw1 |= hb << 16;
    }

    if (t == 255) {
      *(f32x4*)(out + (size_t)rb * 1024 + cu0) = hold;  // final fp32 state
    } else {
      // write-through to L3 (agent-coherent), no L2 dirty line
      u32x2 hv; hv[0] = hw0; hv[1] = hw1;
      asm volatile("global_store_dwordx2 %0, %1, off sc1"
                   :: "v"(hout + (size_t)rb * 1024 + cu0), "v"(hv) : "memory");
    }

    // ---- rg-group barrier (64 blocks), fence-free:
    asm volatile("s_waitcnt vmcnt(0)" ::: "memory");  // sc1 stores acked at L3
    __syncthreads();                                  // all waves drained
    if (tid == 0)
      (void)__hip_atomic_fetch_add(&flags[blockIdx.x << 4], 1,
                                   __ATOMIC_RELAXED, __HIP_MEMORY_SCOPE_AGENT);
    if (w == 0) {
      const int want = t + 1;
      while (__hip_atomic_load(&flags[((rg << 6) | lane) << 4], __ATOMIC_RELAXED,
                               __HIP_MEMORY_SCOPE_AGENT) < want) {}
    }
    __syncthreads();
  }

  // carry fp32 state to next chunk (if any)
  if (t0 + nsteps < 256)
    *(f32x4*)(h32 + (size_t)rb * 1024 + cu0) = hold;
}

extern "C" void kernel_launch(void* const* d_in, const int* in_sizes, int n_in,
                              void* d_out, int out_size, void* d_ws, size_t ws_size,
                              hipStream_t stream) {
  (void)in_sizes; (void)n_in; (void)out_size;
  const float* x    = (const float*)d_in[0];   // (256,256,512)
  const float* Wk   = (const float*)d_in[1];   // (512,3072)
  const float* Rk   = (const float*)d_in[2];   // (1024,3072)
  const float* bias = (const float*)d_in[3];   // (2,3072)
  float* out = (float*)d_out;

  char* ws = (char*)d_ws;
  unsigned short* Wt    = (unsigned short*)(ws + 0);         // 3,145,728 B
  unsigned short* Ut    = (unsigned short*)(ws + 3145728);   // 6,291,456 B
  float*          biasC = (float*)(ws + 9437184);            // 16,384 B
  unsigned short* hbf0  = (unsigned short*)(ws + 9453568);   // 524,288 B
  unsigned short* hbf1  = (unsigned short*)(ws + 9977856);   // 524,288 B
  float*          h32   = (float*)(ws + 10502144);           // 1,048,576 B
  int*            flags = (int*)(ws + 11550720);             // 16,384 B (padded)
  unsigned short* xp    = (unsigned short*)(ws + 11567104);  // CH * 1,572,864 B

  const size_t fixed_end = 11567104;
  int CH = 256;
  while (CH > 1 && fixed_end + (size_t)CH * 1572864 > ws_size) CH >>= 1;

  static int attr_set = 0;
  if (!attr_set) {
    (void)hipFuncSetAttribute((const void*)gru_persist,
                              hipFuncAttributeMaxDynamicSharedMemorySize, 98304);
    attr_set = 1;
  }

  tconv<<<dim3(96, 16), 256, 0, stream>>>(Wk, Wt, 512, 3072);
  tconv<<<dim3(96, 32), 256, 0, stream>>>(Rk, Ut, 1024, 3072);
  bprep<<<4, 256, 0, stream>>>(bias, biasC);
  hinit<<<256, 256, 0, stream>>>(hbf0, h32, flags);

  const int nch = 256 / CH;
  for (int c = 0; c < nch; ++c) {
    xproj<<<dim3(24, CH * 2), 256, 0, stream>>>(x, Wt, xp, c * CH);
    gru_persist<<<256, 256, 98304, stream>>>(xp, Ut, biasC, hbf0, hbf1, h32,
                                             flags, out, c * CH, CH);
  }
}